// Round 3
// baseline (351.075 us; speedup 1.0000x reference)
//
#include <hip/hip_runtime.h>

#define N 128
#define NN (N * N)          // 16384
#define M 2048

typedef float fvec4 __attribute__((ext_vector_type(4)));

// ---------------------------------------------------------------------------
// Prep: evc0, evc1 (Gram-Schmidt), softplus+normalized eigenvalues.
// sqrt(lam_p) folded into the stored eigenvectors.
// ws layout: [0..128) e0r' | [128..256) e0i' | [256..384) e1r' | [384..512) e1i'
//            [512 ..) per-block partials (2 floats each; A then B)
// ---------------------------------------------------------------------------
__device__ __forceinline__ float block_reduce128(float v, float* red, int i) {
    __syncthreads();
    red[i] = v;
    __syncthreads();
    for (int off = 64; off > 0; off >>= 1) {
        if (i < off) red[i] += red[i + off];
        __syncthreads();
    }
    return red[0];
}

__global__ void prep_kernel(const float* __restrict__ theta,
                            const float* __restrict__ evl,
                            float* __restrict__ ws) {
    __shared__ float red[N];
    const int i = threadIdx.x;   // 128 threads

    float c0r = theta[i], c0i = theta[N + i];
    float s0 = block_reduce128(c0r * c0r + c0i * c0i, red, i);
    float inv0 = rsqrtf(s0);
    float a0r = c0r * inv0, a0i = c0i * inv0;

    float c1r = theta[2 * N + i], c1i = theta[3 * N + i];
    float dr = block_reduce128(a0r * c1r + a0i * c1i, red, i);
    float di = block_reduce128(a0r * c1i - a0i * c1r, red, i);
    c1r -= dr * a0r - di * a0i;
    c1i -= dr * a0i + di * a0r;

    float s1 = block_reduce128(c1r * c1r + c1i * c1i, red, i);
    float inv1 = rsqrtf(s1);

    float l0 = log1pf(expf(evl[0]));   // softplus
    float l1 = log1pf(expf(evl[1]));
    float inl = rsqrtf(l0 * l0 + l1 * l1);
    float sc0 = sqrtf(l0 * inl);       // sqrt(lam0)
    float sc1 = sqrtf(l1 * inl);       // sqrt(lam1)

    ws[i]         = a0r * sc0;
    ws[N + i]     = a0i * sc0;
    ws[2 * N + i] = c1r * inv1 * sc1;
    ws[3 * N + i] = c1i * inv1 * sc1;
}

// ---------------------------------------------------------------------------
// Main: grid (M, 2). blockIdx.y==0 -> basis_re (cached loads, L3-resident),
//       blockIdx.y==1 -> basis_im (non-temporal, HBM stream).
// Each block reduces ONE real array against H:
//   vX = sum_p (+/-) sum_i E_p[i] * ( sum_j x[i,j] * conj(E_p[j]) )
// Streams fully decoupled: independent vmcnt flow per block, depth-6 pipeline.
// v = vA + i*vB is recombined in reduce_kernel.
// ---------------------------------------------------------------------------
#define DOT(comp, D)                                             \
    d0r = fmaf((D).comp, E0r.comp, d0r);                         \
    d0i = fmaf((D).comp, E0i.comp, d0i);                         \
    d1r = fmaf((D).comp, E1r.comp, d1r);                         \
    d1i = fmaf((D).comp, E1i.comp, d1i);

#define STEP(c, D)                                               \
    {                                                            \
        float d0r = 0.f, d0i = 0.f, d1r = 0.f, d1i = 0.f;        \
        DOT(x, D) DOT(y, D) DOT(z, D) DOT(w, D)                  \
        const int irow = bi0 + 8 * (c);                          \
        const float er0 = le[irow],       ei0 = le[128 + irow];  \
        const float er1 = le[256 + irow], ei1 = le[384 + irow];  \
        v0r = fmaf(er0, d0r, v0r); v0r = fmaf(ei0, d0i, v0r);    \
        v0i = fmaf(ei0, d0r, v0i); v0i = fmaf(-er0, d0i, v0i);   \
        v1r = fmaf(er1, d1r, v1r); v1r = fmaf(ei1, d1i, v1r);    \
        v1i = fmaf(ei1, d1r, v1i); v1i = fmaf(-er1, d1i, v1i);   \
    }

#define PF(D, c)                                                 \
    {                                                            \
        D = NT ? __builtin_nontemporal_load(srck + t + 256 * (c))\
               : srck[t + 256 * (c)];                            \
    }                                                            \
    __builtin_amdgcn_sched_barrier(0);

template<bool NT>
__device__ __forceinline__ void stream_body(
        const fvec4* __restrict__ srck, const float* __restrict__ ws,
        float* __restrict__ le, int t, float& outR, float& outI) {
    // prologue: 6 loads in flight before anything else
    fvec4 D0, D1, D2, D3, D4, D5;
    PF(D0, 0) PF(D1, 1) PF(D2, 2) PF(D3, 3) PF(D4, 4) PF(D5, 5)

    if (t < 128) ((fvec4*)le)[t] = ((const fvec4*)ws)[t];
    __syncthreads();

    const int j4  = t & 31;    // float4 column index, chunk-invariant
    const int bi0 = t >> 5;    // base row, i = bi0 + 8*c
    const fvec4* e4 = (const fvec4*)le;
    const fvec4 E0r = e4[j4],      E0i = e4[32 + j4];
    const fvec4 E1r = e4[64 + j4], E1i = e4[96 + j4];
    __builtin_amdgcn_sched_barrier(0);

    float v0r = 0.f, v0i = 0.f, v1r = 0.f, v1i = 0.f;

    STEP(0,  D0) PF(D0, 6)
    STEP(1,  D1) PF(D1, 7)
    STEP(2,  D2) PF(D2, 8)
    STEP(3,  D3) PF(D3, 9)
    STEP(4,  D4) PF(D4, 10)
    STEP(5,  D5) PF(D5, 11)
    STEP(6,  D0) PF(D0, 12)
    STEP(7,  D1) PF(D1, 13)
    STEP(8,  D2) PF(D2, 14)
    STEP(9,  D3) PF(D3, 15)
    STEP(10, D4)
    STEP(11, D5)
    STEP(12, D0)
    STEP(13, D1)
    STEP(14, D2)
    STEP(15, D3)

    outR = v0r - v1r;
    outI = v0i - v1i;
}

__global__ __launch_bounds__(256, 8) void main_kernel(
        const fvec4* __restrict__ br, const fvec4* __restrict__ bi,
        const float* __restrict__ ws, float* __restrict__ partial) {
    __shared__ __align__(16) float le[4 * N];
    __shared__ float swr[4], swi[4];
    const int t = threadIdx.x;
    const int k = blockIdx.x;
    const int which = blockIdx.y;

    float vr, vi;
    if (which == 0) {
        stream_body<false>(br + (size_t)k * (NN / 4), ws, le, t, vr, vi);
    } else {
        stream_body<true>(bi + (size_t)k * (NN / 4), ws, le, t, vr, vi);
    }

    // wave-64 reduce, then cross-wave via LDS
    for (int off = 32; off > 0; off >>= 1) {
        vr += __shfl_down(vr, off);
        vi += __shfl_down(vi, off);
    }
    const int wave = t >> 6, lane = t & 63;
    if (lane == 0) { swr[wave] = vr; swi[wave] = vi; }
    __syncthreads();
    if (t == 0) {
        const int idx = which * M + k;
        partial[2 * idx]     = swr[0] + swr[1] + swr[2] + swr[3];
        partial[2 * idx + 1] = swi[0] + swi[1] + swi[2] + swi[3];
    }
}

// ---------------------------------------------------------------------------
// Combine: v_k = vA_k + i*vB_k;  out = sum_k |v_k|^2
// ---------------------------------------------------------------------------
__global__ __launch_bounds__(256) void reduce_kernel(
        const float* __restrict__ partial, float* __restrict__ out) {
    __shared__ float sw[4];
    const int t = threadIdx.x;
    float s = 0.f;
    #pragma unroll
    for (int r = 0; r < M / 256; ++r) {
        const int k = t + 256 * r;
        const float vAr = partial[2 * k],           vAi = partial[2 * k + 1];
        const float vBr = partial[2 * (M + k)],     vBi = partial[2 * (M + k) + 1];
        const float Re = vAr - vBi;
        const float Im = vAi + vBr;
        s = fmaf(Re, Re, s);
        s = fmaf(Im, Im, s);
    }
    for (int off = 32; off > 0; off >>= 1) s += __shfl_down(s, off);
    if ((t & 63) == 0) sw[t >> 6] = s;
    __syncthreads();
    if (t == 0) out[0] = sw[0] + sw[1] + sw[2] + sw[3];
}

extern "C" void kernel_launch(void* const* d_in, const int* in_sizes, int n_in,
                              void* d_out, int out_size, void* d_ws, size_t ws_size,
                              hipStream_t stream) {
    const float* basis_re = (const float*)d_in[0];
    const float* basis_im = (const float*)d_in[1];
    const float* theta    = (const float*)d_in[2];
    const float* evl      = (const float*)d_in[3];
    float* out = (float*)d_out;
    float* ws  = (float*)d_ws;   // [0..512) vectors | [512..8704) partials

    prep_kernel<<<1, 128, 0, stream>>>(theta, evl, ws);
    main_kernel<<<dim3(M, 2), 256, 0, stream>>>((const fvec4*)basis_re,
                                                (const fvec4*)basis_im,
                                                ws, ws + 512);
    reduce_kernel<<<1, 256, 0, stream>>>(ws + 512, out);
}

// Round 4
// 295.773 us; speedup vs baseline: 1.1870x; 1.1870x over previous
//
#include <hip/hip_runtime.h>

#define N 128
#define NN (N * N)          // 16384
#define M 2048

typedef float fvec4 __attribute__((ext_vector_type(4)));

// ---------------------------------------------------------------------------
// Prep: evc0, evc1 (Gram-Schmidt), softplus+normalized eigenvalues.
// sqrt(lam_p) folded into the stored eigenvectors.
// ws layout: [0..128) e0r' | [128..256) e0i' | [256..384) e1r' | [384..512) e1i'
//            [512 ..) per-block partials (2 floats each; A then B)
// ---------------------------------------------------------------------------
__device__ __forceinline__ float block_reduce128(float v, float* red, int i) {
    __syncthreads();
    red[i] = v;
    __syncthreads();
    for (int off = 64; off > 0; off >>= 1) {
        if (i < off) red[i] += red[i + off];
        __syncthreads();
    }
    return red[0];
}

__global__ void prep_kernel(const float* __restrict__ theta,
                            const float* __restrict__ evl,
                            float* __restrict__ ws) {
    __shared__ float red[N];
    const int i = threadIdx.x;   // 128 threads

    float c0r = theta[i], c0i = theta[N + i];
    float s0 = block_reduce128(c0r * c0r + c0i * c0i, red, i);
    float inv0 = rsqrtf(s0);
    float a0r = c0r * inv0, a0i = c0i * inv0;

    float c1r = theta[2 * N + i], c1i = theta[3 * N + i];
    float dr = block_reduce128(a0r * c1r + a0i * c1i, red, i);
    float di = block_reduce128(a0r * c1i - a0i * c1r, red, i);
    c1r -= dr * a0r - di * a0i;
    c1i -= dr * a0i + di * a0r;

    float s1 = block_reduce128(c1r * c1r + c1i * c1i, red, i);
    float inv1 = rsqrtf(s1);

    float l0 = log1pf(expf(evl[0]));   // softplus
    float l1 = log1pf(expf(evl[1]));
    float inl = rsqrtf(l0 * l0 + l1 * l1);
    float sc0 = sqrtf(l0 * inl);       // sqrt(lam0)
    float sc1 = sqrtf(l1 * inl);       // sqrt(lam1)

    ws[i]         = a0r * sc0;
    ws[N + i]     = a0i * sc0;
    ws[2 * N + i] = c1r * inv1 * sc1;
    ws[3 * N + i] = c1i * inv1 * sc1;
}

// ---------------------------------------------------------------------------
// Main: grid (2, M) -- x is the FAST dispatch dimension, so the br-block and
// bi-block of the same operator k launch adjacently (both populations
// co-resident on every CU; memory-side pattern matches round 2's working
// L3 partition: br normal loads -> L3-resident, bi nt loads -> HBM stream).
// Each block reduces ONE real array with an independent depth-8 pipeline:
//   vX = sum_p (+/-) sum_i E_p[i] * ( sum_j x[i,j] * conj(E_p[j]) )
// v = vA + i*vB recombined in reduce_kernel.
// ---------------------------------------------------------------------------
#define DOT(comp, D)                                             \
    d0r = fmaf((D).comp, E0r.comp, d0r);                         \
    d0i = fmaf((D).comp, E0i.comp, d0i);                         \
    d1r = fmaf((D).comp, E1r.comp, d1r);                         \
    d1i = fmaf((D).comp, E1i.comp, d1i);

#define STEP(c, D)                                               \
    {                                                            \
        float d0r = 0.f, d0i = 0.f, d1r = 0.f, d1i = 0.f;        \
        DOT(x, D) DOT(y, D) DOT(z, D) DOT(w, D)                  \
        const int irow = bi0 + 8 * (c);                          \
        const float er0 = le[irow],       ei0 = le[128 + irow];  \
        const float er1 = le[256 + irow], ei1 = le[384 + irow];  \
        v0r = fmaf(er0, d0r, v0r); v0r = fmaf(ei0, d0i, v0r);    \
        v0i = fmaf(ei0, d0r, v0i); v0i = fmaf(-er0, d0i, v0i);   \
        v1r = fmaf(er1, d1r, v1r); v1r = fmaf(ei1, d1i, v1r);    \
        v1i = fmaf(ei1, d1r, v1i); v1i = fmaf(-er1, d1i, v1i);   \
    }

#define PF(D, c)                                                 \
    {                                                            \
        D = NT ? __builtin_nontemporal_load(srck + t + 256 * (c))\
               : srck[t + 256 * (c)];                            \
    }                                                            \
    __builtin_amdgcn_sched_barrier(0);

template<bool NT>
__device__ __forceinline__ void stream_body(
        const fvec4* __restrict__ srck, const float* __restrict__ ws,
        float* __restrict__ le, int t, float& outR, float& outI) {
    // prologue: depth-8 pipeline, 8 wave-loads in flight before anything else
    fvec4 D0, D1, D2, D3, D4, D5, D6, D7;
    PF(D0, 0) PF(D1, 1) PF(D2, 2) PF(D3, 3)
    PF(D4, 4) PF(D5, 5) PF(D6, 6) PF(D7, 7)

    if (t < 128) ((fvec4*)le)[t] = ((const fvec4*)ws)[t];
    __syncthreads();

    const int j4  = t & 31;    // float4 column index, chunk-invariant
    const int bi0 = t >> 5;    // base row, i = bi0 + 8*c
    const fvec4* e4 = (const fvec4*)le;
    const fvec4 E0r = e4[j4],      E0i = e4[32 + j4];
    const fvec4 E1r = e4[64 + j4], E1i = e4[96 + j4];
    __builtin_amdgcn_sched_barrier(0);

    float v0r = 0.f, v0i = 0.f, v1r = 0.f, v1i = 0.f;

    STEP(0,  D0) PF(D0, 8)
    STEP(1,  D1) PF(D1, 9)
    STEP(2,  D2) PF(D2, 10)
    STEP(3,  D3) PF(D3, 11)
    STEP(4,  D4) PF(D4, 12)
    STEP(5,  D5) PF(D5, 13)
    STEP(6,  D6) PF(D6, 14)
    STEP(7,  D7) PF(D7, 15)
    STEP(8,  D0)
    STEP(9,  D1)
    STEP(10, D2)
    STEP(11, D3)
    STEP(12, D4)
    STEP(13, D5)
    STEP(14, D6)
    STEP(15, D7)

    outR = v0r - v1r;
    outI = v0i - v1i;
}

__global__ __launch_bounds__(256, 6) void main_kernel(
        const fvec4* __restrict__ br, const fvec4* __restrict__ bi,
        const float* __restrict__ ws, float* __restrict__ partial) {
    __shared__ __align__(16) float le[4 * N];
    __shared__ float swr[4], swi[4];
    const int t = threadIdx.x;
    const int k = blockIdx.y;        // operator index
    const int which = blockIdx.x;    // 0 = br (L3), 1 = bi (HBM/nt)

    float vr, vi;
    if (which == 0) {
        stream_body<false>(br + (size_t)k * (NN / 4), ws, le, t, vr, vi);
    } else {
        stream_body<true>(bi + (size_t)k * (NN / 4), ws, le, t, vr, vi);
    }

    // wave-64 reduce, then cross-wave via LDS
    for (int off = 32; off > 0; off >>= 1) {
        vr += __shfl_down(vr, off);
        vi += __shfl_down(vi, off);
    }
    const int wave = t >> 6, lane = t & 63;
    if (lane == 0) { swr[wave] = vr; swi[wave] = vi; }
    __syncthreads();
    if (t == 0) {
        const int idx = which * M + k;
        partial[2 * idx]     = swr[0] + swr[1] + swr[2] + swr[3];
        partial[2 * idx + 1] = swi[0] + swi[1] + swi[2] + swi[3];
    }
}

// ---------------------------------------------------------------------------
// Combine: v_k = vA_k + i*vB_k;  out = sum_k |v_k|^2
// ---------------------------------------------------------------------------
__global__ __launch_bounds__(256) void reduce_kernel(
        const float* __restrict__ partial, float* __restrict__ out) {
    __shared__ float sw[4];
    const int t = threadIdx.x;
    float s = 0.f;
    #pragma unroll
    for (int r = 0; r < M / 256; ++r) {
        const int k = t + 256 * r;
        const float vAr = partial[2 * k],           vAi = partial[2 * k + 1];
        const float vBr = partial[2 * (M + k)],     vBi = partial[2 * (M + k) + 1];
        const float Re = vAr - vBi;
        const float Im = vAi + vBr;
        s = fmaf(Re, Re, s);
        s = fmaf(Im, Im, s);
    }
    for (int off = 32; off > 0; off >>= 1) s += __shfl_down(s, off);
    if ((t & 63) == 0) sw[t >> 6] = s;
    __syncthreads();
    if (t == 0) out[0] = sw[0] + sw[1] + sw[2] + sw[3];
}

extern "C" void kernel_launch(void* const* d_in, const int* in_sizes, int n_in,
                              void* d_out, int out_size, void* d_ws, size_t ws_size,
                              hipStream_t stream) {
    const float* basis_re = (const float*)d_in[0];
    const float* basis_im = (const float*)d_in[1];
    const float* theta    = (const float*)d_in[2];
    const float* evl      = (const float*)d_in[3];
    float* out = (float*)d_out;
    float* ws  = (float*)d_ws;   // [0..512) vectors | [512..8704) partials

    prep_kernel<<<1, 128, 0, stream>>>(theta, evl, ws);
    main_kernel<<<dim3(2, M), 256, 0, stream>>>((const fvec4*)basis_re,
                                                (const fvec4*)basis_im,
                                                ws, ws + 512);
    reduce_kernel<<<1, 256, 0, stream>>>(ws + 512, out);
}

// Round 5
// 271.897 us; speedup vs baseline: 1.2912x; 1.0878x over previous
//
#include <hip/hip_runtime.h>

#define N 128
#define NN (N * N)          // 16384
#define M 2048

typedef float fvec4 __attribute__((ext_vector_type(4)));

// ---------------------------------------------------------------------------
// Prep: evc0, evc1 (Gram-Schmidt), softplus+normalized eigenvalues.
// sqrt(lam_p) folded into the stored eigenvectors.
// ws layout: [0..128) e0r' | [128..256) e0i' | [256..384) e1r' | [384..512) e1i'
//            [512 ..) per-block partials (2 floats each)
// ---------------------------------------------------------------------------
__device__ __forceinline__ float block_reduce128(float v, float* red, int i) {
    __syncthreads();
    red[i] = v;
    __syncthreads();
    for (int off = 64; off > 0; off >>= 1) {
        if (i < off) red[i] += red[i + off];
        __syncthreads();
    }
    return red[0];
}

__global__ void prep_kernel(const float* __restrict__ theta,
                            const float* __restrict__ evl,
                            float* __restrict__ ws) {
    __shared__ float red[N];
    const int i = threadIdx.x;   // 128 threads

    float c0r = theta[i], c0i = theta[N + i];
    float s0 = block_reduce128(c0r * c0r + c0i * c0i, red, i);
    float inv0 = rsqrtf(s0);
    float a0r = c0r * inv0, a0i = c0i * inv0;

    float c1r = theta[2 * N + i], c1i = theta[3 * N + i];
    float dr = block_reduce128(a0r * c1r + a0i * c1i, red, i);
    float di = block_reduce128(a0r * c1i - a0i * c1r, red, i);
    c1r -= dr * a0r - di * a0i;
    c1i -= dr * a0i + di * a0r;

    float s1 = block_reduce128(c1r * c1r + c1i * c1i, red, i);
    float inv1 = rsqrtf(s1);

    float l0 = log1pf(expf(evl[0]));   // softplus
    float l1 = log1pf(expf(evl[1]));
    float inl = rsqrtf(l0 * l0 + l1 * l1);
    float sc0 = sqrtf(l0 * inl);       // sqrt(lam0)
    float sc1 = sqrtf(l1 * inl);       // sqrt(lam1)

    ws[i]         = a0r * sc0;
    ws[N + i]     = a0i * sc0;
    ws[2 * N + i] = c1r * inv1 * sc1;
    ws[3 * N + i] = c1i * inv1 * sc1;
}

// ---------------------------------------------------------------------------
// Main: one block per operator k (round-2 memory pattern: each wave reads
// br normally -> L3-resident, bi non-temporally -> HBM stream).
// NEW: loads are VOLATILE INLINE ASM (IR passes cannot sink/collapse them)
// with counted s_waitcnt vmcnt(8) + sched_barrier(0) discipline.
// Depth-5 pair pipeline = 10 outstanding dwordx4 loads per wave.
// ---------------------------------------------------------------------------
#define GLD(dst, ptr)                                                       \
    asm volatile("global_load_dwordx4 %0, %1, off"                          \
                 : "=&v"(dst) : "v"(ptr) : "memory")
#define GLDNT(dst, ptr)                                                     \
    asm volatile("global_load_dwordx4 %0, %1, off nt"                       \
                 : "=&v"(dst) : "v"(ptr) : "memory")
#define VMWAIT(n)                                                           \
    asm volatile("s_waitcnt vmcnt(" #n ")" ::: "memory");                   \
    __builtin_amdgcn_sched_barrier(0)

#define ELEM(comp, A, B)                                         \
    {                                                            \
        a0r = fmaf((A).comp, E0r.comp, a0r);                     \
        a0r = fmaf(-(B).comp, E0i.comp, a0r);                    \
        a0i = fmaf(-(A).comp, E0i.comp, a0i);                    \
        a0i = fmaf(-(B).comp, E0r.comp, a0i);                    \
        a1r = fmaf((A).comp, E1r.comp, a1r);                     \
        a1r = fmaf(-(B).comp, E1i.comp, a1r);                    \
        a1i = fmaf(-(A).comp, E1i.comp, a1i);                    \
        a1i = fmaf(-(B).comp, E1r.comp, a1i);                    \
    }

#define STEP(c, A, B)                                            \
    {                                                            \
        float a0r = 0.f, a0i = 0.f, a1r = 0.f, a1i = 0.f;        \
        ELEM(x, A, B) ELEM(y, A, B) ELEM(z, A, B) ELEM(w, A, B)  \
        const int irow = bi0 + 8 * (c);                          \
        const float er0 = le[irow],       ei0 = le[128 + irow];  \
        const float er1 = le[256 + irow], ei1 = le[384 + irow];  \
        v0r = fmaf(er0, a0r, v0r); v0r = fmaf(-ei0, a0i, v0r);   \
        v0i = fmaf(er0, a0i, v0i); v0i = fmaf(ei0, a0r, v0i);    \
        v1r = fmaf(er1, a1r, v1r); v1r = fmaf(-ei1, a1i, v1r);   \
        v1i = fmaf(er1, a1i, v1i); v1i = fmaf(ei1, a1r, v1i);    \
    }

#define PFPAIR(A, B, c)                                          \
    GLD(A, pbr + 256 * (c));                                     \
    GLDNT(B, pbi + 256 * (c));

__global__ __launch_bounds__(256, 6) void main_kernel(
        const fvec4* __restrict__ br, const fvec4* __restrict__ bi,
        const float* __restrict__ ws, float* __restrict__ partial) {
    __shared__ __align__(16) float le[4 * N];   // e0r' | e0i' | e1r' | e1i'
    __shared__ float swr[4], swi[4];
    const int t = threadIdx.x;
    const int k = blockIdx.x;

    // stage eigenvectors into LDS first; barrier drains vmcnt+lgkmcnt to 0
    if (t < 128) ((fvec4*)le)[t] = ((const fvec4*)ws)[t];
    __syncthreads();

    const int j4  = t & 31;    // float4 column index, chunk-invariant
    const int bi0 = t >> 5;    // base row, i = bi0 + 8*c
    const fvec4* e4 = (const fvec4*)le;
    const fvec4 E0r = e4[j4],      E0i = e4[32 + j4];
    const fvec4 E1r = e4[64 + j4], E1i = e4[96 + j4];

    const fvec4* pbr = br + (size_t)k * (NN / 4) + t;
    const fvec4* pbi = bi + (size_t)k * (NN / 4) + t;

    // prologue: chunks 0..4 in flight (10 loads, 5 pairs)
    fvec4 A0, B0, A1, B1, A2, B2, A3, B3, A4, B4;
    PFPAIR(A0, B0, 0)
    PFPAIR(A1, B1, 1)
    PFPAIR(A2, B2, 2)
    PFPAIR(A3, B3, 3)
    PFPAIR(A4, B4, 4)

    float v0r = 0.f, v0i = 0.f, v1r = 0.f, v1i = 0.f;

    // steady state: wait for oldest pair, compute, refill same buffer
    VMWAIT(8); STEP(0,  A0, B0) PFPAIR(A0, B0, 5)
    VMWAIT(8); STEP(1,  A1, B1) PFPAIR(A1, B1, 6)
    VMWAIT(8); STEP(2,  A2, B2) PFPAIR(A2, B2, 7)
    VMWAIT(8); STEP(3,  A3, B3) PFPAIR(A3, B3, 8)
    VMWAIT(8); STEP(4,  A4, B4) PFPAIR(A4, B4, 9)
    VMWAIT(8); STEP(5,  A0, B0) PFPAIR(A0, B0, 10)
    VMWAIT(8); STEP(6,  A1, B1) PFPAIR(A1, B1, 11)
    VMWAIT(8); STEP(7,  A2, B2) PFPAIR(A2, B2, 12)
    VMWAIT(8); STEP(8,  A3, B3) PFPAIR(A3, B3, 13)
    VMWAIT(8); STEP(9,  A4, B4) PFPAIR(A4, B4, 14)
    VMWAIT(8); STEP(10, A0, B0) PFPAIR(A0, B0, 15)
    // tail: drain
    VMWAIT(8); STEP(11, A1, B1)
    VMWAIT(6); STEP(12, A2, B2)
    VMWAIT(4); STEP(13, A3, B3)
    VMWAIT(2); STEP(14, A4, B4)
    VMWAIT(0); STEP(15, A0, B0)

    float vr = v0r - v1r;
    float vi = v0i - v1i;

    // wave-64 reduce, then cross-wave via LDS
    for (int off = 32; off > 0; off >>= 1) {
        vr += __shfl_down(vr, off);
        vi += __shfl_down(vi, off);
    }
    const int wave = t >> 6, lane = t & 63;
    if (lane == 0) { swr[wave] = vr; swi[wave] = vi; }
    __syncthreads();
    if (t == 0) {
        partial[2 * k]     = swr[0] + swr[1] + swr[2] + swr[3];
        partial[2 * k + 1] = swi[0] + swi[1] + swi[2] + swi[3];
    }
}

// ---------------------------------------------------------------------------
// Final: out = sum_k |v_k|^2
// ---------------------------------------------------------------------------
__global__ __launch_bounds__(256) void reduce_kernel(
        const float* __restrict__ partial, float* __restrict__ out) {
    __shared__ float sw[4];
    const int t = threadIdx.x;
    float s = 0.f;
    #pragma unroll
    for (int r = 0; r < M / 256; ++r) {
        const int k = t + 256 * r;
        const float vr = partial[2 * k], vi = partial[2 * k + 1];
        s = fmaf(vr, vr, s);
        s = fmaf(vi, vi, s);
    }
    for (int off = 32; off > 0; off >>= 1) s += __shfl_down(s, off);
    if ((t & 63) == 0) sw[t >> 6] = s;
    __syncthreads();
    if (t == 0) out[0] = sw[0] + sw[1] + sw[2] + sw[3];
}

extern "C" void kernel_launch(void* const* d_in, const int* in_sizes, int n_in,
                              void* d_out, int out_size, void* d_ws, size_t ws_size,
                              hipStream_t stream) {
    const float* basis_re = (const float*)d_in[0];
    const float* basis_im = (const float*)d_in[1];
    const float* theta    = (const float*)d_in[2];
    const float* evl      = (const float*)d_in[3];
    float* out = (float*)d_out;
    float* ws  = (float*)d_ws;   // [0..512) vectors | [512..4608) partials

    prep_kernel<<<1, 128, 0, stream>>>(theta, evl, ws);
    main_kernel<<<M, 256, 0, stream>>>((const fvec4*)basis_re,
                                       (const fvec4*)basis_im,
                                       ws, ws + 512);
    reduce_kernel<<<1, 256, 0, stream>>>(ws + 512, out);
}